// Round 10
// baseline (579.036 us; speedup 1.0000x reference)
//
#include <hip/hip_runtime.h>
#include <hip/hip_bf16.h>

// EdgeProposer R15: barrier-free main kernel via row-split waves.
// R14 post-mortem: epilogue fix bought ~1 us -> not the stall. Accounting:
// 78% of wall is no-issue stall; R12-vs-R13 prices per-step barrier overhead
// at ~2.5k cyc (skew of 8 coupled waves + post-barrier L2 burst + drain).
// R15: each wave owns 32 rows x 320 cols x K=512. Private LDS tile
// (producer==consumer) -> ZERO __syncthreads. Per-kk order B->G->M->S keeps
// bfr vmcnt waits never queued behind random gathers (in-order vmcnt).
// Epilogue fully wave-private (16-row slabs, tables packed bf16, 2-lane
// C3/C4). LDS 4x10752B=43008. Prep chain reverted to R12 structure
// (prep_kernel emits bel16; prep_bst3 = R12 prep_bst + packed table write).
// Tripwires: WRITE ~33.8MB (spill); fail-read: dur>=125us -> barrier theory
// wrong -> measurement round next.

#define DD 512
#define K3 1536
#define ROWS 128
#define LDACT 328
#define BUFS 12288
#define WSLOT 5376   // shorts per wave slot (10752B): tiles 2x1024 / acts 16x328

typedef short bf16x8 __attribute__((ext_vector_type(8)));
typedef float f32x4 __attribute__((ext_vector_type(4)));

__device__ inline float b2f(short s) {
    union { float f; unsigned u; } v;
    v.u = ((unsigned)(unsigned short)s) << 16;
    return v.f;
}
__device__ inline short f2b(float f) {   // RNE
    union { float fl; unsigned u; } v;
    v.fl = f;
    unsigned x = v.u;
    unsigned r = x + 0x7fffu + ((x >> 16) & 1u);
    return (short)(r >> 16);
}
__device__ inline short babsdiff(short a, short b) {
    union { float f; unsigned u; } v;
    v.f = b2f(a) - b2f(b);
    return (short)((v.u & 0x7fffffffu) >> 16);
}
__device__ __forceinline__ bf16x8 babs8(bf16x8 s, bf16x8 t) {
    bf16x8 a;
#pragma unroll
    for (int j = 0; j < 8; j++) a[j] = babsdiff(s[j], t[j]);
    return a;
}

// ---------------- old (R10) helpers for fallback ----------------
__device__ __forceinline__ int sidx32(int seg, int rt, int lane) {
    return ((seg * 8 + rt) * 64 + lane) * 8;
}
__device__ __forceinline__ void writeStage(short* buf, int rtw, int lnw, int kcb,
                                           bf16x8 s0, bf16x8 s1,
                                           bf16x8 t0, bf16x8 t1) {
    bf16x8 a0 = babs8(s0, t0), a1 = babs8(s1, t1);
    int l0 = kcb * 16 + lnw, l1 = l0 + 16;
    *(bf16x8*)&buf[sidx32(0, rtw, l0)] = s0;
    *(bf16x8*)&buf[sidx32(0, rtw, l1)] = s1;
    *(bf16x8*)&buf[sidx32(1, rtw, l0)] = t0;
    *(bf16x8*)&buf[sidx32(1, rtw, l1)] = t1;
    *(bf16x8*)&buf[sidx32(2, rtw, l0)] = a0;
    *(bf16x8*)&buf[sidx32(2, rtw, l1)] = a1;
}
__device__ __forceinline__ void stage_f32(const float* bs, const float* bt,
                                          short* buf, int rtw, int lnw, int kcb) {
#pragma unroll
    for (int c = 0; c < 2; c++) {
        bf16x8 sb, tb, ab;
#pragma unroll
        for (int h = 0; h < 2; h++) {
            float4 s4 = ((const float4*)bs)[c * 2 + h];
            float4 t4 = ((const float4*)bt)[c * 2 + h];
            float ss[4] = {s4.x, s4.y, s4.z, s4.w};
            float tt[4] = {t4.x, t4.y, t4.z, t4.w};
#pragma unroll
            for (int e = 0; e < 4; e++) {
                int j = h * 4 + e;
                sb[j] = f2b(ss[e]);
                tb[j] = f2b(tt[e]);
                ab[j] = f2b(fabsf(ss[e] - tt[e]));
            }
        }
        int l16 = (kcb + c) * 16 + lnw;
        *(bf16x8*)&buf[sidx32(0, rtw, l16)] = sb;
        *(bf16x8*)&buf[sidx32(1, rtw, l16)] = tb;
        *(bf16x8*)&buf[sidx32(2, rtw, l16)] = ab;
    }
}

// ---- workspace layout (shorts) ----
#define WT_ELEMS (320 * 1536)
#define P2T_OFF WT_ELEMS
#define R2T_OFF (WT_ELEMS + 64 * 128)
#define PREP_TOT (WT_ELEMS + 2 * 64 * 128)
#define BEL_ELEMS (8192 * 512)
#define BEL_OFF PREP_TOT
#define TBL_ELEMS (8192 * 4 * 16 * 8)   // packed bf16 table, 8MB each

// weights + beliefs -> bf16 layouts (R12 version)
__global__ void prep_kernel(const float* __restrict__ pw1,
                            const float* __restrict__ dw1,
                            const float* __restrict__ rw1,
                            const float* __restrict__ pw2,
                            const float* __restrict__ rw2,
                            const float* __restrict__ beliefs,
                            short* __restrict__ ws, int total8) {
    int i8 = blockIdx.x * 256 + threadIdx.x;
    if (i8 >= total8) return;
    int i = i8 * 8;
    bf16x8 o;
    if (i < WT_ELEMS) {
        int n = i / K3, k = i - n * K3;
        const float* src;
        int stride, off;
        if (n < 128)      { src = pw1; stride = 128; off = n; }
        else if (n < 192) { src = dw1; stride = 64;  off = n - 128; }
        else              { src = rw1; stride = 128; off = n - 192; }
#pragma unroll
        for (int j = 0; j < 8; j++) o[j] = f2b(src[(k + j) * stride + off]);
    } else if (i < R2T_OFF) {
        int jj = i - P2T_OFF;
        int n = jj >> 7, k = jj & 127;
#pragma unroll
        for (int j = 0; j < 8; j++) o[j] = f2b(pw2[(k + j) * 64 + n]);
    } else if (i < PREP_TOT) {
        int jj = i - R2T_OFF;
        int n = jj >> 7, k = jj & 127;
#pragma unroll
        for (int j = 0; j < 8; j++) o[j] = f2b(rw2[(k + j) * 64 + n]);
    } else {
        const float4* b4 = (const float4*)(beliefs + (i - BEL_OFF));
        float4 x = b4[0], y = b4[1];
        float v[8] = {x.x, x.y, x.z, x.w, y.x, y.y, y.z, y.w};
#pragma unroll
        for (int j = 0; j < 8; j++) o[j] = f2b(v[j]);
    }
    *(bf16x8*)&ws[i] = o;
}

// ---- prep_bst3: packed bf16 tables from bel16 (R12 prep_bst structure).
// grid 256: block b -> table (b&1), rows (b>>1)*64.
__global__ __launch_bounds__(256) void prep_bst3(
    const short* __restrict__ bel16, const short* __restrict__ WT,
    short* __restrict__ BsT, short* __restrict__ BtT) {
    const int tb = blockIdx.x & 1;
    const int r0 = (blockIdx.x >> 1) * 64;
    const int t = threadIdx.x;
    const int w = t >> 6, lane = t & 63, q = lane >> 4, ln = lane & 15;
    short* Bo = tb ? BtT : BsT;
    const int koff = tb ? 512 : 0;

    f32x4 acc[5][4];
#pragma unroll
    for (int ct = 0; ct < 5; ct++)
#pragma unroll
        for (int rt = 0; rt < 4; rt++) acc[ct][rt] = (f32x4)(0.f);

#pragma unroll
    for (int k0 = 0; k0 < 512; k0 += 128)
#pragma unroll
        for (int kk = 0; kk < 4; kk++) {
            bf16x8 bfr[5];
#pragma unroll
            for (int ct = 0; ct < 5; ct++)
                bfr[ct] = *(const bf16x8*)(WT + (size_t)(w * 80 + ct * 16 + ln) * K3 +
                                           koff + k0 + kk * 32 + q * 8);
#pragma unroll
            for (int rt = 0; rt < 4; rt++) {
                bf16x8 af = *(const bf16x8*)(bel16 +
                    (size_t)(r0 + rt * 16 + ln) * DD + k0 + kk * 32 + q * 8);
#pragma unroll
                for (int ct = 0; ct < 5; ct++)
                    acc[ct][rt] = __builtin_amdgcn_mfma_f32_16x16x32_bf16(
                        af, bfr[ct], acc[ct][rt], 0, 0, 0);
            }
        }
    // packed write: Bo[((r*4+w)*16+ln)*8 + ct], col = w*80 + ct*16 + ln
#pragma unroll
    for (int rt = 0; rt < 4; rt++)
#pragma unroll
        for (int i = 0; i < 4; i++) {
            int r = r0 + rt * 16 + q * 4 + i;
            size_t base = ((size_t)(r * 4 + w) * 16 + ln) * 8;
#pragma unroll
            for (int ct = 0; ct < 5; ct++)
                Bo[base + ct] = f2b(acc[ct][rt][i]);
        }
}

// ---- R15 main kernel: barrier-free, row-split waves ----
__global__ __launch_bounds__(256, 2) void edge_main4(
    const short* __restrict__ bel16,
    const int* __restrict__ src_idx, const int* __restrict__ tgt_idx,
    const short* __restrict__ BsT, const short* __restrict__ BtT,
    const float* __restrict__ pb1, const float* __restrict__ db1,
    const float* __restrict__ rb1,
    const float* __restrict__ pb2, const float* __restrict__ pw3,
    const float* __restrict__ pb3,
    const float* __restrict__ dw2, const float* __restrict__ db2,
    const float* __restrict__ rb2,
    const short* __restrict__ WT, const short* __restrict__ pw2T,
    const short* __restrict__ rw2T,
    float* __restrict__ out, int N)
{
    __shared__ __align__(16) short sm[4 * WSLOT];   // 43008 B, wave-private slots
    const int t = threadIdx.x;
    const int r0 = blockIdx.x * ROWS;
    const int w = t >> 6, lane = t & 63, q = lane >> 4, ln = lane & 15;
    short* slot = sm + w * WSLOT;

    // staging role: lane covers row lr = lane>>1 of the wave's 32, k-half kh
    const int lr = lane >> 1, kh = lane & 1;
    const int myrow = r0 + w * 32 + lr;
    const size_t srow = (size_t)src_idx[myrow] * DD + kh * 16;
    const size_t trow = (size_t)tgt_idx[myrow] * DD + kh * 16;
    const int rtb = lr >> 4, lnw = lr & 15;
    const int d0 = (rtb * 64 + (kh * 2) * 16 + lnw) * 8;
    const int d1 = (rtb * 64 + (kh * 2 + 1) * 16 + lnw) * 8;

    f32x4 acc[20][2];
#pragma unroll
    for (int ct = 0; ct < 20; ct++) {
        acc[ct][0] = (f32x4)(0.f);
        acc[ct][1] = (f32x4)(0.f);
    }

    // prologue: g(0) -> stage tile0 -> issue g(1)
    bf16x8 ps0 = *(const bf16x8*)(bel16 + srow);
    bf16x8 ps1 = *(const bf16x8*)(bel16 + srow + 8);
    bf16x8 pt0 = *(const bf16x8*)(bel16 + trow);
    bf16x8 pt1 = *(const bf16x8*)(bel16 + trow + 8);
    *(bf16x8*)&slot[d0] = babs8(ps0, pt0);
    *(bf16x8*)&slot[d1] = babs8(ps1, pt1);
    ps0 = *(const bf16x8*)(bel16 + srow + 32);
    ps1 = *(const bf16x8*)(bel16 + srow + 40);
    pt0 = *(const bf16x8*)(bel16 + trow + 32);
    pt1 = *(const bf16x8*)(bel16 + trow + 40);

    // K-loop: 16 kk of 32, wave-private double buffer, NO barriers.
    // Per-iter order B -> G -> M -> S keeps bfr waits off the gather queue.
    for (int kk = 0; kk < 16; ++kk) {
        const short* tc = slot + (kk & 1) * 1024;
        short* tn = slot + ((kk & 1) ^ 1) * 1024;
        // B: 20 bfr loads (oldest this iter)
        bf16x8 bfr[20];
#pragma unroll
        for (int ct = 0; ct < 20; ct++)
            bfr[ct] = *(const bf16x8*)(WT + (size_t)(ct * 16 + ln) * K3 +
                                       1024 + kk * 32 + q * 8);
        __builtin_amdgcn_sched_barrier(0);
        // G: gathers for kk+2 (newest; bfr waits never force them)
        bf16x8 ns0, ns1, nt0, nt1;
        if (kk < 14) {
            ns0 = *(const bf16x8*)(bel16 + srow + (kk + 2) * 32);
            ns1 = *(const bf16x8*)(bel16 + srow + (kk + 2) * 32 + 8);
            nt0 = *(const bf16x8*)(bel16 + trow + (kk + 2) * 32);
            nt1 = *(const bf16x8*)(bel16 + trow + (kk + 2) * 32 + 8);
        }
        __builtin_amdgcn_sched_barrier(0);
        // M: 40 MFMAs
        bf16x8 af0 = *(const bf16x8*)&tc[(0 * 64 + lane) * 8];
        bf16x8 af1 = *(const bf16x8*)&tc[(1 * 64 + lane) * 8];
        __builtin_amdgcn_s_setprio(1);
#pragma unroll
        for (int ct = 0; ct < 20; ct++) {
            acc[ct][0] = __builtin_amdgcn_mfma_f32_16x16x32_bf16(
                af0, bfr[ct], acc[ct][0], 0, 0, 0);
            acc[ct][1] = __builtin_amdgcn_mfma_f32_16x16x32_bf16(
                af1, bfr[ct], acc[ct][1], 0, 0, 0);
        }
        __builtin_amdgcn_s_setprio(0);
        // S: stage tile kk+1 from g(kk+1) (issued last iter; wait ~free)
        if (kk < 15) {
            *(bf16x8*)&tn[d0] = babs8(ps0, pt0);
            *(bf16x8*)&tn[d1] = babs8(ps1, pt1);
            ps0 = ns0; ps1 = ns1; pt0 = nt0; pt1 = nt1;
        }
    }

    // ---- epilogue: wave-private 16-row slabs (hh = rt), zero barriers ----
    short (*acts)[LDACT] = (short (*)[LDACT])slot;   // aliases tiles (done)
#pragma unroll
    for (int hh = 0; hh < 2; hh++) {
        // bias + tables + relu -> acts[16][320]
#pragma unroll
        for (int i = 0; i < 4; i++) {
            int gr = r0 + w * 32 + hh * 16 + q * 4 + i;
            int si = src_idx[gr], ti = tgt_idx[gr];
#pragma unroll
            for (int cg = 0; cg < 4; cg++) {
                bf16x8 bs8 = *(const bf16x8*)(BsT +
                    ((size_t)(si * 4 + cg) * 16 + ln) * 8);
                bf16x8 bt8 = *(const bf16x8*)(BtT +
                    ((size_t)(ti * 4 + cg) * 16 + ln) * 8);
#pragma unroll
                for (int c5 = 0; c5 < 5; c5++) {
                    int ct = cg * 5 + c5;
                    int col = ct * 16 + ln;
                    float bias = (col < 128) ? pb1[col]
                               : (col < 192) ? db1[col - 128]
                                             : rb1[col - 192];
                    float v = acc[ct][hh][i] + b2f(bs8[c5]) + b2f(bt8[c5]) + bias;
                    acts[q * 4 + i][col] = f2b(fmaxf(v, 0.f));
                }
            }
        }

        // C1: relations = relu1_r[16x128] @ rw2 + rb2 (acts cols 192..319)
        {
            f32x4 rc[4];
#pragma unroll
            for (int c2 = 0; c2 < 4; c2++) rc[c2] = (f32x4)(0.f);
#pragma unroll
            for (int ks = 0; ks < 4; ks++) {
                bf16x8 afr = *(const bf16x8*)&acts[ln][192 + ks * 32 + q * 8];
#pragma unroll
                for (int c2 = 0; c2 < 4; c2++) {
                    bf16x8 bfr2 = *(const bf16x8*)(rw2T + (c2 * 16 + ln) * 128 +
                                                   ks * 32 + q * 8);
                    rc[c2] = __builtin_amdgcn_mfma_f32_16x16x32_bf16(
                        afr, bfr2, rc[c2], 0, 0, 0);
                }
            }
            float* rel = out + 2 * (size_t)N;
#pragma unroll
            for (int c2 = 0; c2 < 4; c2++) {
                int col = c2 * 16 + ln;
                float bias = rb2[col];
#pragma unroll
                for (int i = 0; i < 4; i++) {
                    int grow = r0 + w * 32 + hh * 16 + q * 4 + i;
                    rel[(size_t)grow * 64 + col] = rc[c2][i] + bias;
                }
            }
        }

        // C2: pc = relu1_p[16x128] @ pw2 (acts cols 0..127)
        f32x4 pc[4];
        {
#pragma unroll
            for (int c2 = 0; c2 < 4; c2++) pc[c2] = (f32x4)(0.f);
#pragma unroll
            for (int ks = 0; ks < 4; ks++) {
                bf16x8 afr = *(const bf16x8*)&acts[ln][0 + ks * 32 + q * 8];
#pragma unroll
                for (int c2 = 0; c2 < 4; c2++) {
                    bf16x8 bfr2 = *(const bf16x8*)(pw2T + (c2 * 16 + ln) * 128 +
                                                   ks * 32 + q * 8);
                    pc[c2] = __builtin_amdgcn_mfma_f32_16x16x32_bf16(
                        afr, bfr2, pc[c2], 0, 0, 0);
                }
            }
        }
        // h2 = relu(pc + pb2) -> acts cols 0..63 (after C2 reads; same wave)
#pragma unroll
        for (int c2 = 0; c2 < 4; c2++) {
            int col = c2 * 16 + ln;
            float bias = pb2[col];
#pragma unroll
            for (int i = 0; i < 4; i++)
                acts[q * 4 + i][col] = f2b(fmaxf(pc[c2][i] + bias, 0.f));
        }

        // C3: probs (acts[.][0..63]); C4: dirs (acts[.][128..191]).
        // 2 lanes per row within the wave's 16 rows; shfl_xor(1) reduce.
        {
            int role = lane >> 5;          // 0: probs, 1: directions
            int rl = (lane & 31) >> 1;     // row 0..15
            int kq = lane & 1;             // 32-k half
            float s = 0.f;
            if (role == 0) {
#pragma unroll
                for (int j = 0; j < 32; j++)
                    s += b2f(acts[rl][kq * 32 + j]) * pw3[kq * 32 + j];
            } else {
#pragma unroll
                for (int j = 0; j < 32; j++)
                    s += b2f(acts[rl][128 + kq * 32 + j]) * dw2[kq * 32 + j];
            }
            s += __shfl_xor(s, 1);
            if (kq == 0) {
                int grow = r0 + w * 32 + hh * 16 + rl;
                if (role == 0) {
                    float pr = 1.f / (1.f + __expf(-(s + pb3[0])));
                    out[grow] = pr;
                } else {
                    float dir = (1.f / (1.f + __expf(-(s + db2[0])))) *
                                1.57079632679489662f;
                    out[(size_t)N + grow] = dir;
                }
            }
        }
    }
}

// ---------------- old (R10) main kernel: ws fallback ----------------
template<bool BF>
__global__ __launch_bounds__(256, 2) void edge_main(
    const float* __restrict__ beliefs, const short* __restrict__ bel16,
    const int* __restrict__ src_idx, const int* __restrict__ tgt_idx,
    const float* __restrict__ pb1, const float* __restrict__ db1,
    const float* __restrict__ rb1,
    const float* __restrict__ pb2, const float* __restrict__ pw3,
    const float* __restrict__ pb3,
    const float* __restrict__ dw2, const float* __restrict__ db2,
    const float* __restrict__ rb2,
    const short* __restrict__ WT, const short* __restrict__ pw2T,
    const short* __restrict__ rw2T,
    float* __restrict__ out, int N)
{
    __shared__ __align__(16) char smem_u[49152];
    short* As2 = (short*)smem_u;
    short (*acts)[LDACT] = (short (*)[LDACT])smem_u;
    int* sIdx = (int*)smem_u;
    int* tIdx = sIdx + ROWS;

    const int t = threadIdx.x;
    const int r0 = blockIdx.x * ROWS;
    const int w = t >> 6, lane = t & 63, q = lane >> 4, ln = lane & 15;

    if (t < ROWS) sIdx[t] = src_idx[r0 + t] * DD;
    else tIdx[t - ROWS] = tgt_idx[r0 + t - ROWS] * DD;
    __syncthreads();

    const int rrow = t >> 1, kh = t & 1;
    const int rtw = rrow >> 4, lnw = rrow & 15;
    const int kcb = kh * 2;
    const int srow = sIdx[rrow], trow = tIdx[rrow];
    __syncthreads();

    f32x4 acc[5][8];
#pragma unroll
    for (int ct = 0; ct < 5; ct++)
#pragma unroll
        for (int rt = 0; rt < 8; rt++) acc[ct][rt] = (f32x4)(0.f);

    bf16x8 bfr0[5];
#pragma unroll
    for (int ct = 0; ct < 5; ct++) {
        int col = w * 80 + ct * 16 + ln;
        bfr0[ct] = *(const bf16x8*)(WT + (size_t)col * K3 + q * 8);
    }
    if constexpr (BF) {
        const bf16x8* pS = (const bf16x8*)(bel16 + srow + kh * 16);
        const bf16x8* pT = (const bf16x8*)(bel16 + trow + kh * 16);
        writeStage(As2, rtw, lnw, kcb, pS[0], pS[1], pT[0], pT[1]);
    } else {
        stage_f32(beliefs + srow + kh * 16, beliefs + trow + kh * 16,
                  As2, rtw, lnw, kcb);
    }
    __syncthreads();

    for (int step = 0; step < 16; ++step) {
        short* bufC = As2 + (step & 1) * BUFS;
        short* bufN = As2 + ((step & 1) ^ 1) * BUFS;
        const int k0 = step * 32;
        const bool pf = (step < 15);
        bf16x8 ns0, ns1, nt0, nt1;

#pragma unroll
        for (int seg = 0; seg < 3; seg++) {
            bf16x8 bfr[5];
            if (seg == 0) {
#pragma unroll
                for (int ct = 0; ct < 5; ct++) bfr[ct] = bfr0[ct];
            } else {
#pragma unroll
                for (int ct = 0; ct < 5; ct++) {
                    int col = w * 80 + ct * 16 + ln;
                    bfr[ct] = *(const bf16x8*)(WT + (size_t)col * K3 +
                                               seg * DD + k0 + q * 8);
                }
            }
            if (seg == 2) {
                __builtin_amdgcn_sched_barrier(0);
                if (pf) {
                    if constexpr (BF) {
                        const bf16x8* pS = (const bf16x8*)(bel16 + srow + k0 + 32 + kh * 16);
                        const bf16x8* pT = (const bf16x8*)(bel16 + trow + k0 + 32 + kh * 16);
                        ns0 = pS[0]; ns1 = pS[1]; nt0 = pT[0]; nt1 = pT[1];
                    }
#pragma unroll
                    for (int ct = 0; ct < 5; ct++) {
                        int col = w * 80 + ct * 16 + ln;
                        bfr0[ct] = *(const bf16x8*)(WT + (size_t)col * K3 +
                                                    k0 + 32 + q * 8);
                    }
                }
                __builtin_amdgcn_sched_barrier(0);
            }
            __builtin_amdgcn_s_setprio(1);
#pragma unroll
            for (int rt = 0; rt < 8; rt++) {
                bf16x8 af = *(const bf16x8*)&bufC[sidx32(seg, rt, lane)];
#pragma unroll
                for (int ct = 0; ct < 5; ct++)
                    acc[ct][rt] = __builtin_amdgcn_mfma_f32_16x16x32_bf16(
                        af, bfr[ct], acc[ct][rt], 0, 0, 0);
            }
            __builtin_amdgcn_s_setprio(0);
        }
        if constexpr (BF) {
            if (pf) writeStage(bufN, rtw, lnw, kcb, ns0, ns1, nt0, nt1);
        } else {
            if (pf) stage_f32(beliefs + srow + k0 + 32 + kh * 16,
                              beliefs + trow + k0 + 32 + kh * 16,
                              bufN, rtw, lnw, kcb);
        }
        __syncthreads();
    }

#pragma unroll
    for (int h = 0; h < 2; h++) {
#pragma unroll
        for (int ct = 0; ct < 5; ct++) {
            int col = w * 80 + ct * 16 + ln;
            float bias = (col < 128) ? pb1[col]
                       : (col < 192) ? db1[col - 128]
                                     : rb1[col - 192];
#pragma unroll
            for (int rt4 = 0; rt4 < 4; rt4++)
#pragma unroll
                for (int i = 0; i < 4; i++) {
                    int lrow = rt4 * 16 + q * 4 + i;
                    float v = acc[ct][h * 4 + rt4][i] + bias;
                    acts[lrow][col] = f2b(fmaxf(v, 0.f));
                }
        }
        __syncthreads();
        {
            f32x4 rc[4];
#pragma unroll
            for (int rt = 0; rt < 4; rt++) rc[rt] = (f32x4)(0.f);
#pragma unroll
            for (int ks = 0; ks < 4; ks++) {
                bf16x8 bfr = *(const bf16x8*)(rw2T + (w * 16 + ln) * 128 +
                                              ks * 32 + q * 8);
#pragma unroll
                for (int rt = 0; rt < 4; rt++) {
                    bf16x8 afr = *(const bf16x8*)&acts[rt * 16 + ln][192 + ks * 32 + q * 8];
                    rc[rt] = __builtin_amdgcn_mfma_f32_16x16x32_bf16(afr, bfr, rc[rt], 0, 0, 0);
                }
            }
            int col = w * 16 + ln;
            float bias = rb2[col];
            float* rel = out + 2 * (size_t)N;
#pragma unroll
            for (int rt = 0; rt < 4; rt++)
#pragma unroll
                for (int i = 0; i < 4; i++) {
                    int grow = r0 + h * 64 + rt * 16 + q * 4 + i;
                    rel[(size_t)grow * 64 + col] = rc[rt][i] + bias;
                }
        }
        f32x4 pc[4];
        {
#pragma unroll
            for (int rt = 0; rt < 4; rt++) pc[rt] = (f32x4)(0.f);
#pragma unroll
            for (int ks = 0; ks < 4; ks++) {
                bf16x8 bfr = *(const bf16x8*)(pw2T + (w * 16 + ln) * 128 +
                                              ks * 32 + q * 8);
#pragma unroll
                for (int rt = 0; rt < 4; rt++) {
                    bf16x8 afr = *(const bf16x8*)&acts[rt * 16 + ln][0 + ks * 32 + q * 8];
                    pc[rt] = __builtin_amdgcn_mfma_f32_16x16x32_bf16(afr, bfr, pc[rt], 0, 0, 0);
                }
            }
        }
        __syncthreads();
        {
            int col = w * 16 + ln;
            float bias = pb2[col];
#pragma unroll
            for (int rt = 0; rt < 4; rt++)
#pragma unroll
                for (int i = 0; i < 4; i++) {
                    int lrow = rt * 16 + q * 4 + i;
                    acts[lrow][col] = f2b(fmaxf(pc[rt][i] + bias, 0.f));
                }
        }
        __syncthreads();
        if (t < 64) {
            float s = pb3[0];
#pragma unroll 8
            for (int k = 0; k < 64; k++) s += b2f(acts[t][k]) * pw3[k];
            float pr = 1.f / (1.f + __expf(-s));
            out[r0 + h * 64 + t] = pr;
        } else if (t < 128) {
            int lrow = t - 64;
            float s = db2[0];
#pragma unroll 8
            for (int k = 0; k < 64; k++) s += b2f(acts[lrow][128 + k]) * dw2[k];
            float dir = (1.f / (1.f + __expf(-s))) * 1.57079632679489662f;
            out[(size_t)N + r0 + h * 64 + lrow] = dir;
        }
        __syncthreads();
    }
}

extern "C" void kernel_launch(void* const* d_in, const int* in_sizes, int n_in,
                              void* d_out, int out_size, void* d_ws, size_t ws_size,
                              hipStream_t stream) {
    const float* beliefs = (const float*)d_in[0];
    const int* src = (const int*)d_in[1];
    const int* tgt = (const int*)d_in[2];
    const float* pw1 = (const float*)d_in[3];
    const float* pb1 = (const float*)d_in[4];
    const float* pw2 = (const float*)d_in[5];
    const float* pb2 = (const float*)d_in[6];
    const float* pw3 = (const float*)d_in[7];
    const float* pb3 = (const float*)d_in[8];
    const float* dw1 = (const float*)d_in[9];
    const float* db1 = (const float*)d_in[10];
    const float* dw2 = (const float*)d_in[11];
    const float* db2 = (const float*)d_in[12];
    const float* rw1 = (const float*)d_in[13];
    const float* rb1 = (const float*)d_in[14];
    const float* rw2 = (const float*)d_in[15];
    const float* rb2 = (const float*)d_in[16];

    short* ws = (short*)d_ws;
    short* WT    = ws;
    short* pw2T  = ws + P2T_OFF;
    short* rw2T  = ws + R2T_OFF;
    short* bel16 = ws + BEL_OFF;
    const int N = in_sizes[1];

    const size_t BF_BYTES = (size_t)(PREP_TOT + BEL_ELEMS) * sizeof(short);
    const size_t V2_BYTES = BF_BYTES + (size_t)2 * TBL_ELEMS * sizeof(short);
    const bool useV2 = ws_size >= V2_BYTES;
    const bool useBf = ws_size >= BF_BYTES;

    if (useV2) {
        const int prep8 = (PREP_TOT + BEL_ELEMS) / 8;
        prep_kernel<<<(prep8 + 255) / 256, 256, 0, stream>>>(
            pw1, dw1, rw1, pw2, rw2, beliefs, ws, prep8);
        short* BsT = ws + PREP_TOT + BEL_ELEMS;
        short* BtT = BsT + TBL_ELEMS;
        prep_bst3<<<256, 256, 0, stream>>>(bel16, WT, BsT, BtT);
        edge_main4<<<N / ROWS, 256, 0, stream>>>(
            bel16, src, tgt, BsT, BtT,
            pb1, db1, rb1, pb2, pw3, pb3, dw2, db2, rb2,
            WT, pw2T, rw2T, (float*)d_out, N);
    } else {
        const int prepElems = useBf ? (PREP_TOT + BEL_ELEMS) : PREP_TOT;
        const int prep8 = prepElems / 8;
        prep_kernel<<<(prep8 + 255) / 256, 256, 0, stream>>>(
            pw1, dw1, rw1, pw2, rw2, beliefs, ws, prep8);
        if (useBf)
            edge_main<true><<<N / ROWS, 256, 0, stream>>>(
                beliefs, bel16, src, tgt, pb1, db1, rb1, pb2, pw3, pb3,
                dw2, db2, rb2, WT, pw2T, rw2T, (float*)d_out, N);
        else
            edge_main<false><<<N / ROWS, 256, 0, stream>>>(
                beliefs, bel16, src, tgt, pb1, db1, rb1, pb2, pw3, pb3,
                dw2, db2, rb2, WT, pw2T, rw2T, (float*)d_out, N);
    }
}

// Round 11
// 395.967 us; speedup vs baseline: 1.4623x; 1.4623x over previous
//
#include <hip/hip_runtime.h>
#include <hip/hip_bf16.h>

// EdgeProposer R16: R15 barrier-free structure with the spill fixed.
// R15 post-mortem: bfr[20] (80 VGPR) live across each kk + acc 160 + gathers
// -> spill storm (WRITE 587MB), barrier theory never measured. R16 consumes
// bfr in 4 groups of 5 interleaved with MFMA quarters:
//   B0,B1 -> M0 -> B2 -> M1 -> B3,G -> M2 -> M3 -> S
// Peak live bfr = 2 groups (40 VGPR) + gathers 32 = proven R10 envelope.
// vmcnt: M0 waits B0 (B1 outstanding), M3 waits B3 (only G outstanding),
// S consumes last iter's G (oldest, done). Zero __syncthreads anywhere.
// Tripwire 1: WRITE must return to ~33.8MB (else still spilling -> abandon).
// Fail-read: clean WRITE + dur>=125us -> barrier coupling was NOT the stall
// -> revert to R12/R14 best next round and conclude.

#define DD 512
#define K3 1536
#define ROWS 128
#define LDACT 328
#define BUFS 12288
#define WSLOT 5376   // shorts per wave slot (10752B): tiles 2x1024 / acts 16x328

typedef short bf16x8 __attribute__((ext_vector_type(8)));
typedef float f32x4 __attribute__((ext_vector_type(4)));

__device__ inline float b2f(short s) {
    union { float f; unsigned u; } v;
    v.u = ((unsigned)(unsigned short)s) << 16;
    return v.f;
}
__device__ inline short f2b(float f) {   // RNE
    union { float fl; unsigned u; } v;
    v.fl = f;
    unsigned x = v.u;
    unsigned r = x + 0x7fffu + ((x >> 16) & 1u);
    return (short)(r >> 16);
}
__device__ inline short babsdiff(short a, short b) {
    union { float f; unsigned u; } v;
    v.f = b2f(a) - b2f(b);
    return (short)((v.u & 0x7fffffffu) >> 16);
}
__device__ __forceinline__ bf16x8 babs8(bf16x8 s, bf16x8 t) {
    bf16x8 a;
#pragma unroll
    for (int j = 0; j < 8; j++) a[j] = babsdiff(s[j], t[j]);
    return a;
}

// ---------------- old (R10) helpers for fallback ----------------
__device__ __forceinline__ int sidx32(int seg, int rt, int lane) {
    return ((seg * 8 + rt) * 64 + lane) * 8;
}
__device__ __forceinline__ void writeStage(short* buf, int rtw, int lnw, int kcb,
                                           bf16x8 s0, bf16x8 s1,
                                           bf16x8 t0, bf16x8 t1) {
    bf16x8 a0 = babs8(s0, t0), a1 = babs8(s1, t1);
    int l0 = kcb * 16 + lnw, l1 = l0 + 16;
    *(bf16x8*)&buf[sidx32(0, rtw, l0)] = s0;
    *(bf16x8*)&buf[sidx32(0, rtw, l1)] = s1;
    *(bf16x8*)&buf[sidx32(1, rtw, l0)] = t0;
    *(bf16x8*)&buf[sidx32(1, rtw, l1)] = t1;
    *(bf16x8*)&buf[sidx32(2, rtw, l0)] = a0;
    *(bf16x8*)&buf[sidx32(2, rtw, l1)] = a1;
}
__device__ __forceinline__ void stage_f32(const float* bs, const float* bt,
                                          short* buf, int rtw, int lnw, int kcb) {
#pragma unroll
    for (int c = 0; c < 2; c++) {
        bf16x8 sb, tb, ab;
#pragma unroll
        for (int h = 0; h < 2; h++) {
            float4 s4 = ((const float4*)bs)[c * 2 + h];
            float4 t4 = ((const float4*)bt)[c * 2 + h];
            float ss[4] = {s4.x, s4.y, s4.z, s4.w};
            float tt[4] = {t4.x, t4.y, t4.z, t4.w};
#pragma unroll
            for (int e = 0; e < 4; e++) {
                int j = h * 4 + e;
                sb[j] = f2b(ss[e]);
                tb[j] = f2b(tt[e]);
                ab[j] = f2b(fabsf(ss[e] - tt[e]));
            }
        }
        int l16 = (kcb + c) * 16 + lnw;
        *(bf16x8*)&buf[sidx32(0, rtw, l16)] = sb;
        *(bf16x8*)&buf[sidx32(1, rtw, l16)] = tb;
        *(bf16x8*)&buf[sidx32(2, rtw, l16)] = ab;
    }
}

// ---- workspace layout (shorts) ----
#define WT_ELEMS (320 * 1536)
#define P2T_OFF WT_ELEMS
#define R2T_OFF (WT_ELEMS + 64 * 128)
#define PREP_TOT (WT_ELEMS + 2 * 64 * 128)
#define BEL_ELEMS (8192 * 512)
#define BEL_OFF PREP_TOT
#define TBL_ELEMS (8192 * 4 * 16 * 8)   // packed bf16 table, 8MB each

// weights + beliefs -> bf16 layouts (R12 version)
__global__ void prep_kernel(const float* __restrict__ pw1,
                            const float* __restrict__ dw1,
                            const float* __restrict__ rw1,
                            const float* __restrict__ pw2,
                            const float* __restrict__ rw2,
                            const float* __restrict__ beliefs,
                            short* __restrict__ ws, int total8) {
    int i8 = blockIdx.x * 256 + threadIdx.x;
    if (i8 >= total8) return;
    int i = i8 * 8;
    bf16x8 o;
    if (i < WT_ELEMS) {
        int n = i / K3, k = i - n * K3;
        const float* src;
        int stride, off;
        if (n < 128)      { src = pw1; stride = 128; off = n; }
        else if (n < 192) { src = dw1; stride = 64;  off = n - 128; }
        else              { src = rw1; stride = 128; off = n - 192; }
#pragma unroll
        for (int j = 0; j < 8; j++) o[j] = f2b(src[(k + j) * stride + off]);
    } else if (i < R2T_OFF) {
        int jj = i - P2T_OFF;
        int n = jj >> 7, k = jj & 127;
#pragma unroll
        for (int j = 0; j < 8; j++) o[j] = f2b(pw2[(k + j) * 64 + n]);
    } else if (i < PREP_TOT) {
        int jj = i - R2T_OFF;
        int n = jj >> 7, k = jj & 127;
#pragma unroll
        for (int j = 0; j < 8; j++) o[j] = f2b(rw2[(k + j) * 64 + n]);
    } else {
        const float4* b4 = (const float4*)(beliefs + (i - BEL_OFF));
        float4 x = b4[0], y = b4[1];
        float v[8] = {x.x, x.y, x.z, x.w, y.x, y.y, y.z, y.w};
#pragma unroll
        for (int j = 0; j < 8; j++) o[j] = f2b(v[j]);
    }
    *(bf16x8*)&ws[i] = o;
}

// ---- prep_bst3: packed bf16 tables from bel16 (R12 prep_bst structure).
// grid 256: block b -> table (b&1), rows (b>>1)*64.
__global__ __launch_bounds__(256) void prep_bst3(
    const short* __restrict__ bel16, const short* __restrict__ WT,
    short* __restrict__ BsT, short* __restrict__ BtT) {
    const int tb = blockIdx.x & 1;
    const int r0 = (blockIdx.x >> 1) * 64;
    const int t = threadIdx.x;
    const int w = t >> 6, lane = t & 63, q = lane >> 4, ln = lane & 15;
    short* Bo = tb ? BtT : BsT;
    const int koff = tb ? 512 : 0;

    f32x4 acc[5][4];
#pragma unroll
    for (int ct = 0; ct < 5; ct++)
#pragma unroll
        for (int rt = 0; rt < 4; rt++) acc[ct][rt] = (f32x4)(0.f);

#pragma unroll
    for (int k0 = 0; k0 < 512; k0 += 128)
#pragma unroll
        for (int kk = 0; kk < 4; kk++) {
            bf16x8 bfr[5];
#pragma unroll
            for (int ct = 0; ct < 5; ct++)
                bfr[ct] = *(const bf16x8*)(WT + (size_t)(w * 80 + ct * 16 + ln) * K3 +
                                           koff + k0 + kk * 32 + q * 8);
#pragma unroll
            for (int rt = 0; rt < 4; rt++) {
                bf16x8 af = *(const bf16x8*)(bel16 +
                    (size_t)(r0 + rt * 16 + ln) * DD + k0 + kk * 32 + q * 8);
#pragma unroll
                for (int ct = 0; ct < 5; ct++)
                    acc[ct][rt] = __builtin_amdgcn_mfma_f32_16x16x32_bf16(
                        af, bfr[ct], acc[ct][rt], 0, 0, 0);
            }
        }
#pragma unroll
    for (int rt = 0; rt < 4; rt++)
#pragma unroll
        for (int i = 0; i < 4; i++) {
            int r = r0 + rt * 16 + q * 4 + i;
            size_t base = ((size_t)(r * 4 + w) * 16 + ln) * 8;
#pragma unroll
            for (int ct = 0; ct < 5; ct++)
                Bo[base + ct] = f2b(acc[ct][rt][i]);
        }
}

// ---- R16 main kernel: barrier-free, row-split waves, grouped bfr ----
__global__ __launch_bounds__(256, 2) void edge_main4(
    const short* __restrict__ bel16,
    const int* __restrict__ src_idx, const int* __restrict__ tgt_idx,
    const short* __restrict__ BsT, const short* __restrict__ BtT,
    const float* __restrict__ pb1, const float* __restrict__ db1,
    const float* __restrict__ rb1,
    const float* __restrict__ pb2, const float* __restrict__ pw3,
    const float* __restrict__ pb3,
    const float* __restrict__ dw2, const float* __restrict__ db2,
    const float* __restrict__ rb2,
    const short* __restrict__ WT, const short* __restrict__ pw2T,
    const short* __restrict__ rw2T,
    float* __restrict__ out, int N)
{
    __shared__ __align__(16) short sm[4 * WSLOT];   // 43008 B, wave-private slots
    const int t = threadIdx.x;
    const int r0 = blockIdx.x * ROWS;
    const int w = t >> 6, lane = t & 63, q = lane >> 4, ln = lane & 15;
    short* slot = sm + w * WSLOT;

    // staging role: lane covers row lr = lane>>1 of the wave's 32, k-half kh
    const int lr = lane >> 1, kh = lane & 1;
    const int myrow = r0 + w * 32 + lr;
    const size_t srow = (size_t)src_idx[myrow] * DD + kh * 16;
    const size_t trow = (size_t)tgt_idx[myrow] * DD + kh * 16;
    const int rtb = lr >> 4, lnw = lr & 15;
    const int d0 = (rtb * 64 + (kh * 2) * 16 + lnw) * 8;
    const int d1 = (rtb * 64 + (kh * 2 + 1) * 16 + lnw) * 8;

    f32x4 acc[20][2];
#pragma unroll
    for (int ct = 0; ct < 20; ct++) {
        acc[ct][0] = (f32x4)(0.f);
        acc[ct][1] = (f32x4)(0.f);
    }

    // prologue: g(0) -> stage tile0 -> issue g(1)
    bf16x8 ps0 = *(const bf16x8*)(bel16 + srow);
    bf16x8 ps1 = *(const bf16x8*)(bel16 + srow + 8);
    bf16x8 pt0 = *(const bf16x8*)(bel16 + trow);
    bf16x8 pt1 = *(const bf16x8*)(bel16 + trow + 8);
    *(bf16x8*)&slot[d0] = babs8(ps0, pt0);
    *(bf16x8*)&slot[d1] = babs8(ps1, pt1);
    ps0 = *(const bf16x8*)(bel16 + srow + 32);
    ps1 = *(const bf16x8*)(bel16 + srow + 40);
    pt0 = *(const bf16x8*)(bel16 + trow + 32);
    pt1 = *(const bf16x8*)(bel16 + trow + 40);

    // K-loop: 16 kk of 32, wave-private double buffer, NO barriers.
    // B0,B1 -> M0 -> B2 -> M1 -> B3,G -> M2 -> M3 -> S.
    for (int kk = 0; kk < 16; ++kk) {
        const short* tc = slot + (kk & 1) * 1024;
        short* tn = slot + ((kk & 1) ^ 1) * 1024;
        const size_t wtb = 1024 + (size_t)kk * 32 + q * 8;

        bf16x8 b0[5], b1[5], b2g[5], b3g[5];
#pragma unroll
        for (int c = 0; c < 5; c++)
            b0[c] = *(const bf16x8*)(WT + (size_t)(c * 16 + ln) * K3 + wtb);
#pragma unroll
        for (int c = 0; c < 5; c++)
            b1[c] = *(const bf16x8*)(WT + (size_t)((5 + c) * 16 + ln) * K3 + wtb);
        __builtin_amdgcn_sched_barrier(0);

        // A-fragments for this tile (shared by all col groups)
        bf16x8 af0 = *(const bf16x8*)&tc[(0 * 64 + lane) * 8];
        bf16x8 af1 = *(const bf16x8*)&tc[(1 * 64 + lane) * 8];

        // M0: cols 0..79 (waits B0; B1 outstanding)
        __builtin_amdgcn_s_setprio(1);
#pragma unroll
        for (int c = 0; c < 5; c++) {
            acc[c][0] = __builtin_amdgcn_mfma_f32_16x16x32_bf16(af0, b0[c], acc[c][0], 0, 0, 0);
            acc[c][1] = __builtin_amdgcn_mfma_f32_16x16x32_bf16(af1, b0[c], acc[c][1], 0, 0, 0);
        }
        __builtin_amdgcn_s_setprio(0);
        __builtin_amdgcn_sched_barrier(0);

        // B2
#pragma unroll
        for (int c = 0; c < 5; c++)
            b2g[c] = *(const bf16x8*)(WT + (size_t)((10 + c) * 16 + ln) * K3 + wtb);
        __builtin_amdgcn_sched_barrier(0);

        // M1: cols 80..159 (waits B1; B2 outstanding)
        __builtin_amdgcn_s_setprio(1);
#pragma unroll
        for (int c = 0; c < 5; c++) {
            acc[5 + c][0] = __builtin_amdgcn_mfma_f32_16x16x32_bf16(af0, b1[c], acc[5 + c][0], 0, 0, 0);
            acc[5 + c][1] = __builtin_amdgcn_mfma_f32_16x16x32_bf16(af1, b1[c], acc[5 + c][1], 0, 0, 0);
        }
        __builtin_amdgcn_s_setprio(0);
        __builtin_amdgcn_sched_barrier(0);

        // B3, then G (gathers newest -> no bfr wait ever drains them)
#pragma unroll
        for (int c = 0; c < 5; c++)
            b3g[c] = *(const bf16x8*)(WT + (size_t)((15 + c) * 16 + ln) * K3 + wtb);
        bf16x8 ns0, ns1, nt0, nt1;
        if (kk < 14) {
            ns0 = *(const bf16x8*)(bel16 + srow + (kk + 2) * 32);
            ns1 = *(const bf16x8*)(bel16 + srow + (kk + 2) * 32 + 8);
            nt0 = *(const bf16x8*)(bel16 + trow + (kk + 2) * 32);
            nt1 = *(const bf16x8*)(bel16 + trow + (kk + 2) * 32 + 8);
        }
        __builtin_amdgcn_sched_barrier(0);

        // M2: cols 160..239 (waits B2; B3+G outstanding)
        __builtin_amdgcn_s_setprio(1);
#pragma unroll
        for (int c = 0; c < 5; c++) {
            acc[10 + c][0] = __builtin_amdgcn_mfma_f32_16x16x32_bf16(af0, b2g[c], acc[10 + c][0], 0, 0, 0);
            acc[10 + c][1] = __builtin_amdgcn_mfma_f32_16x16x32_bf16(af1, b2g[c], acc[10 + c][1], 0, 0, 0);
        }
        // M3: cols 240..319 (waits B3; only G outstanding)
#pragma unroll
        for (int c = 0; c < 5; c++) {
            acc[15 + c][0] = __builtin_amdgcn_mfma_f32_16x16x32_bf16(af0, b3g[c], acc[15 + c][0], 0, 0, 0);
            acc[15 + c][1] = __builtin_amdgcn_mfma_f32_16x16x32_bf16(af1, b3g[c], acc[15 + c][1], 0, 0, 0);
        }
        __builtin_amdgcn_s_setprio(0);
        __builtin_amdgcn_sched_barrier(0);

        // S: stage tile kk+1 from g(kk+1) (issued last iter; wait ~free)
        if (kk < 15) {
            *(bf16x8*)&tn[d0] = babs8(ps0, pt0);
            *(bf16x8*)&tn[d1] = babs8(ps1, pt1);
            ps0 = ns0; ps1 = ns1; pt0 = nt0; pt1 = nt1;
        }
    }

    // ---- epilogue: wave-private 16-row slabs (hh = rt), zero barriers ----
    short (*acts)[LDACT] = (short (*)[LDACT])slot;   // aliases tiles (done)
#pragma unroll
    for (int hh = 0; hh < 2; hh++) {
        // bias + tables + relu -> acts[16][320]
#pragma unroll
        for (int i = 0; i < 4; i++) {
            int gr = r0 + w * 32 + hh * 16 + q * 4 + i;
            int si = src_idx[gr], ti = tgt_idx[gr];
#pragma unroll
            for (int cg = 0; cg < 4; cg++) {
                bf16x8 bs8 = *(const bf16x8*)(BsT +
                    ((size_t)(si * 4 + cg) * 16 + ln) * 8);
                bf16x8 bt8 = *(const bf16x8*)(BtT +
                    ((size_t)(ti * 4 + cg) * 16 + ln) * 8);
#pragma unroll
                for (int c5 = 0; c5 < 5; c5++) {
                    int ct = cg * 5 + c5;
                    int col = ct * 16 + ln;
                    float bias = (col < 128) ? pb1[col]
                               : (col < 192) ? db1[col - 128]
                                             : rb1[col - 192];
                    float v = acc[ct][hh][i] + b2f(bs8[c5]) + b2f(bt8[c5]) + bias;
                    acts[q * 4 + i][col] = f2b(fmaxf(v, 0.f));
                }
            }
        }

        // C1: relations = relu1_r[16x128] @ rw2 + rb2 (acts cols 192..319)
        {
            f32x4 rc[4];
#pragma unroll
            for (int c2 = 0; c2 < 4; c2++) rc[c2] = (f32x4)(0.f);
#pragma unroll
            for (int ks = 0; ks < 4; ks++) {
                bf16x8 afr = *(const bf16x8*)&acts[ln][192 + ks * 32 + q * 8];
#pragma unroll
                for (int c2 = 0; c2 < 4; c2++) {
                    bf16x8 bfr2 = *(const bf16x8*)(rw2T + (c2 * 16 + ln) * 128 +
                                                   ks * 32 + q * 8);
                    rc[c2] = __builtin_amdgcn_mfma_f32_16x16x32_bf16(
                        afr, bfr2, rc[c2], 0, 0, 0);
                }
            }
            float* rel = out + 2 * (size_t)N;
#pragma unroll
            for (int c2 = 0; c2 < 4; c2++) {
                int col = c2 * 16 + ln;
                float bias = rb2[col];
#pragma unroll
                for (int i = 0; i < 4; i++) {
                    int grow = r0 + w * 32 + hh * 16 + q * 4 + i;
                    rel[(size_t)grow * 64 + col] = rc[c2][i] + bias;
                }
            }
        }

        // C2: pc = relu1_p[16x128] @ pw2 (acts cols 0..127)
        f32x4 pc[4];
        {
#pragma unroll
            for (int c2 = 0; c2 < 4; c2++) pc[c2] = (f32x4)(0.f);
#pragma unroll
            for (int ks = 0; ks < 4; ks++) {
                bf16x8 afr = *(const bf16x8*)&acts[ln][0 + ks * 32 + q * 8];
#pragma unroll
                for (int c2 = 0; c2 < 4; c2++) {
                    bf16x8 bfr2 = *(const bf16x8*)(pw2T + (c2 * 16 + ln) * 128 +
                                                   ks * 32 + q * 8);
                    pc[c2] = __builtin_amdgcn_mfma_f32_16x16x32_bf16(
                        afr, bfr2, pc[c2], 0, 0, 0);
                }
            }
        }
        // h2 = relu(pc + pb2) -> acts cols 0..63 (after C2 reads; same wave)
#pragma unroll
        for (int c2 = 0; c2 < 4; c2++) {
            int col = c2 * 16 + ln;
            float bias = pb2[col];
#pragma unroll
            for (int i = 0; i < 4; i++)
                acts[q * 4 + i][col] = f2b(fmaxf(pc[c2][i] + bias, 0.f));
        }

        // C3: probs (acts[.][0..63]); C4: dirs (acts[.][128..191]).
        {
            int role = lane >> 5;          // 0: probs, 1: directions
            int rl = (lane & 31) >> 1;     // row 0..15
            int kq = lane & 1;             // 32-k half
            float s = 0.f;
            if (role == 0) {
#pragma unroll
                for (int j = 0; j < 32; j++)
                    s += b2f(acts[rl][kq * 32 + j]) * pw3[kq * 32 + j];
            } else {
#pragma unroll
                for (int j = 0; j < 32; j++)
                    s += b2f(acts[rl][128 + kq * 32 + j]) * dw2[kq * 32 + j];
            }
            s += __shfl_xor(s, 1);
            if (kq == 0) {
                int grow = r0 + w * 32 + hh * 16 + rl;
                if (role == 0) {
                    float pr = 1.f / (1.f + __expf(-(s + pb3[0])));
                    out[grow] = pr;
                } else {
                    float dir = (1.f / (1.f + __expf(-(s + db2[0])))) *
                                1.57079632679489662f;
                    out[(size_t)N + grow] = dir;
                }
            }
        }
    }
}

// ---------------- old (R10) main kernel: ws fallback ----------------
template<bool BF>
__global__ __launch_bounds__(256, 2) void edge_main(
    const float* __restrict__ beliefs, const short* __restrict__ bel16,
    const int* __restrict__ src_idx, const int* __restrict__ tgt_idx,
    const float* __restrict__ pb1, const float* __restrict__ db1,
    const float* __restrict__ rb1,
    const float* __restrict__ pb2, const float* __restrict__ pw3,
    const float* __restrict__ pb3,
    const float* __restrict__ dw2, const float* __restrict__ db2,
    const float* __restrict__ rb2,
    const short* __restrict__ WT, const short* __restrict__ pw2T,
    const short* __restrict__ rw2T,
    float* __restrict__ out, int N)
{
    __shared__ __align__(16) char smem_u[49152];
    short* As2 = (short*)smem_u;
    short (*acts)[LDACT] = (short (*)[LDACT])smem_u;
    int* sIdx = (int*)smem_u;
    int* tIdx = sIdx + ROWS;

    const int t = threadIdx.x;
    const int r0 = blockIdx.x * ROWS;
    const int w = t >> 6, lane = t & 63, q = lane >> 4, ln = lane & 15;

    if (t < ROWS) sIdx[t] = src_idx[r0 + t] * DD;
    else tIdx[t - ROWS] = tgt_idx[r0 + t - ROWS] * DD;
    __syncthreads();

    const int rrow = t >> 1, kh = t & 1;
    const int rtw = rrow >> 4, lnw = rrow & 15;
    const int kcb = kh * 2;
    const int srow = sIdx[rrow], trow = tIdx[rrow];
    __syncthreads();

    f32x4 acc[5][8];
#pragma unroll
    for (int ct = 0; ct < 5; ct++)
#pragma unroll
        for (int rt = 0; rt < 8; rt++) acc[ct][rt] = (f32x4)(0.f);

    bf16x8 bfr0[5];
#pragma unroll
    for (int ct = 0; ct < 5; ct++) {
        int col = w * 80 + ct * 16 + ln;
        bfr0[ct] = *(const bf16x8*)(WT + (size_t)col * K3 + q * 8);
    }
    if constexpr (BF) {
        const bf16x8* pS = (const bf16x8*)(bel16 + srow + kh * 16);
        const bf16x8* pT = (const bf16x8*)(bel16 + trow + kh * 16);
        writeStage(As2, rtw, lnw, kcb, pS[0], pS[1], pT[0], pT[1]);
    } else {
        stage_f32(beliefs + srow + kh * 16, beliefs + trow + kh * 16,
                  As2, rtw, lnw, kcb);
    }
    __syncthreads();

    for (int step = 0; step < 16; ++step) {
        short* bufC = As2 + (step & 1) * BUFS;
        short* bufN = As2 + ((step & 1) ^ 1) * BUFS;
        const int k0 = step * 32;
        const bool pf = (step < 15);
        bf16x8 ns0, ns1, nt0, nt1;

#pragma unroll
        for (int seg = 0; seg < 3; seg++) {
            bf16x8 bfr[5];
            if (seg == 0) {
#pragma unroll
                for (int ct = 0; ct < 5; ct++) bfr[ct] = bfr0[ct];
            } else {
#pragma unroll
                for (int ct = 0; ct < 5; ct++) {
                    int col = w * 80 + ct * 16 + ln;
                    bfr[ct] = *(const bf16x8*)(WT + (size_t)col * K3 +
                                               seg * DD + k0 + q * 8);
                }
            }
            if (seg == 2) {
                __builtin_amdgcn_sched_barrier(0);
                if (pf) {
                    if constexpr (BF) {
                        const bf16x8* pS = (const bf16x8*)(bel16 + srow + k0 + 32 + kh * 16);
                        const bf16x8* pT = (const bf16x8*)(bel16 + trow + k0 + 32 + kh * 16);
                        ns0 = pS[0]; ns1 = pS[1]; nt0 = pT[0]; nt1 = pT[1];
                    }
#pragma unroll
                    for (int ct = 0; ct < 5; ct++) {
                        int col = w * 80 + ct * 16 + ln;
                        bfr0[ct] = *(const bf16x8*)(WT + (size_t)col * K3 +
                                                    k0 + 32 + q * 8);
                    }
                }
                __builtin_amdgcn_sched_barrier(0);
            }
            __builtin_amdgcn_s_setprio(1);
#pragma unroll
            for (int rt = 0; rt < 8; rt++) {
                bf16x8 af = *(const bf16x8*)&bufC[sidx32(seg, rt, lane)];
#pragma unroll
                for (int ct = 0; ct < 5; ct++)
                    acc[ct][rt] = __builtin_amdgcn_mfma_f32_16x16x32_bf16(
                        af, bfr[ct], acc[ct][rt], 0, 0, 0);
            }
            __builtin_amdgcn_s_setprio(0);
        }
        if constexpr (BF) {
            if (pf) writeStage(bufN, rtw, lnw, kcb, ns0, ns1, nt0, nt1);
        } else {
            if (pf) stage_f32(beliefs + srow + k0 + 32 + kh * 16,
                              beliefs + trow + k0 + 32 + kh * 16,
                              bufN, rtw, lnw, kcb);
        }
        __syncthreads();
    }

#pragma unroll
    for (int h = 0; h < 2; h++) {
#pragma unroll
        for (int ct = 0; ct < 5; ct++) {
            int col = w * 80 + ct * 16 + ln;
            float bias = (col < 128) ? pb1[col]
                       : (col < 192) ? db1[col - 128]
                                     : rb1[col - 192];
#pragma unroll
            for (int rt4 = 0; rt4 < 4; rt4++)
#pragma unroll
                for (int i = 0; i < 4; i++) {
                    int lrow = rt4 * 16 + q * 4 + i;
                    float v = acc[ct][h * 4 + rt4][i] + bias;
                    acts[lrow][col] = f2b(fmaxf(v, 0.f));
                }
        }
        __syncthreads();
        {
            f32x4 rc[4];
#pragma unroll
            for (int rt = 0; rt < 4; rt++) rc[rt] = (f32x4)(0.f);
#pragma unroll
            for (int ks = 0; ks < 4; ks++) {
                bf16x8 bfr = *(const bf16x8*)(rw2T + (w * 16 + ln) * 128 +
                                              ks * 32 + q * 8);
#pragma unroll
                for (int rt = 0; rt < 4; rt++) {
                    bf16x8 afr = *(const bf16x8*)&acts[rt * 16 + ln][192 + ks * 32 + q * 8];
                    rc[rt] = __builtin_amdgcn_mfma_f32_16x16x32_bf16(afr, bfr, rc[rt], 0, 0, 0);
                }
            }
            int col = w * 16 + ln;
            float bias = rb2[col];
            float* rel = out + 2 * (size_t)N;
#pragma unroll
            for (int rt = 0; rt < 4; rt++)
#pragma unroll
                for (int i = 0; i < 4; i++) {
                    int grow = r0 + h * 64 + rt * 16 + q * 4 + i;
                    rel[(size_t)grow * 64 + col] = rc[rt][i] + bias;
                }
        }
        f32x4 pc[4];
        {
#pragma unroll
            for (int rt = 0; rt < 4; rt++) pc[rt] = (f32x4)(0.f);
#pragma unroll
            for (int ks = 0; ks < 4; ks++) {
                bf16x8 bfr = *(const bf16x8*)(pw2T + (w * 16 + ln) * 128 +
                                              ks * 32 + q * 8);
#pragma unroll
                for (int rt = 0; rt < 4; rt++) {
                    bf16x8 afr = *(const bf16x8*)&acts[rt * 16 + ln][0 + ks * 32 + q * 8];
                    pc[rt] = __builtin_amdgcn_mfma_f32_16x16x32_bf16(afr, bfr, pc[rt], 0, 0, 0);
                }
            }
        }
        __syncthreads();
        {
            int col = w * 16 + ln;
            float bias = pb2[col];
#pragma unroll
            for (int rt = 0; rt < 4; rt++)
#pragma unroll
                for (int i = 0; i < 4; i++) {
                    int lrow = rt * 16 + q * 4 + i;
                    acts[lrow][col] = f2b(fmaxf(pc[rt][i] + bias, 0.f));
                }
        }
        __syncthreads();
        if (t < 64) {
            float s = pb3[0];
#pragma unroll 8
            for (int k = 0; k < 64; k++) s += b2f(acts[t][k]) * pw3[k];
            float pr = 1.f / (1.f + __expf(-s));
            out[r0 + h * 64 + t] = pr;
        } else if (t < 128) {
            int lrow = t - 64;
            float s = db2[0];
#pragma unroll 8
            for (int k = 0; k < 64; k++) s += b2f(acts[lrow][128 + k]) * dw2[k];
            float dir = (1.f / (1.f + __expf(-s))) * 1.57079632679489662f;
            out[(size_t)N + r0 + h * 64 + lrow] = dir;
        }
        __syncthreads();
    }
}

extern "C" void kernel_launch(void* const* d_in, const int* in_sizes, int n_in,
                              void* d_out, int out_size, void* d_ws, size_t ws_size,
                              hipStream_t stream) {
    const float* beliefs = (const float*)d_in[0];
    const int* src = (const int*)d_in[1];
    const int* tgt = (const int*)d_in[2];
    const float* pw1 = (const float*)d_in[3];
    const float* pb1 = (const float*)d_in[4];
    const float* pw2 = (const float*)d_in[5];
    const float* pb2 = (const float*)d_in[6];
    const float* pw3 = (const float*)d_in[7];
    const float* pb3 = (const float*)d_in[8];
    const float* dw1 = (const float*)d_in[9];
    const float* db1 = (const float*)d_in[10];
    const float* dw2 = (const float*)d_in[11];
    const float* db2 = (const float*)d_in[12];
    const float* rw1 = (const float*)d_in[13];
    const float* rb1 = (const float*)d_in[14];
    const float* rw2 = (const float*)d_in[15];
    const float* rb2 = (const float*)d_in[16];

    short* ws = (short*)d_ws;
    short* WT    = ws;
    short* pw2T  = ws + P2T_OFF;
    short* rw2T  = ws + R2T_OFF;
    short* bel16 = ws + BEL_OFF;
    const int N = in_sizes[1];

    const size_t BF_BYTES = (size_t)(PREP_TOT + BEL_ELEMS) * sizeof(short);
    const size_t V2_BYTES = BF_BYTES + (size_t)2 * TBL_ELEMS * sizeof(short);
    const bool useV2 = ws_size >= V2_BYTES;
    const bool useBf = ws_size >= BF_BYTES;

    if (useV2) {
        const int prep8 = (PREP_TOT + BEL_ELEMS) / 8;
        prep_kernel<<<(prep8 + 255) / 256, 256, 0, stream>>>(
            pw1, dw1, rw1, pw2, rw2, beliefs, ws, prep8);
        short* BsT = ws + PREP_TOT + BEL_ELEMS;
        short* BtT = BsT + TBL_ELEMS;
        prep_bst3<<<256, 256, 0, stream>>>(bel16, WT, BsT, BtT);
        edge_main4<<<N / ROWS, 256, 0, stream>>>(
            bel16, src, tgt, BsT, BtT,
            pb1, db1, rb1, pb2, pw3, pb3, dw2, db2, rb2,
            WT, pw2T, rw2T, (float*)d_out, N);
    } else {
        const int prepElems = useBf ? (PREP_TOT + BEL_ELEMS) : PREP_TOT;
        const int prep8 = prepElems / 8;
        prep_kernel<<<(prep8 + 255) / 256, 256, 0, stream>>>(
            pw1, dw1, rw1, pw2, rw2, beliefs, ws, prep8);
        if (useBf)
            edge_main<true><<<N / ROWS, 256, 0, stream>>>(
                beliefs, bel16, src, tgt, pb1, db1, rb1, pb2, pw3, pb3,
                dw2, db2, rb2, WT, pw2T, rw2T, (float*)d_out, N);
        else
            edge_main<false><<<N / ROWS, 256, 0, stream>>>(
                beliefs, bel16, src, tgt, pb1, db1, rb1, pb2, pw3, pb3,
                dw2, db2, rb2, WT, pw2T, rw2T, (float*)d_out, N);
    }
}

// Round 12
// 254.111 us; speedup vs baseline: 2.2787x; 1.5582x over previous
//
#include <hip/hip_runtime.h>
#include <hip/hip_bf16.h>

// EdgeProposer R17: best-measured-pieces assembly (after R15/R16 barrier-free
// structure abandoned per tripwire: spill never cleared, theory was built on
// a mis-attribution -- R12<->R13 differed in per-BLOCK cost, not per-step
// barriers; R12's K-loop has only 4 barriers). Components, each previously
// verified in isolation:
//  - edge_main2 = R14's (130.7us): K=512 via Bs/Bt tables, 4x128 K-steps,
//    packed bf16 tables (1 b128/row/table in epilogue), 2-lane C3/C4.
//  - prep chain = R12's shape (total 251.4 best): full prep_kernel
//    (weights + bel16), then prep_bst4 (grid 512, 32 rows/block, acc[5][2])
//    emitting PACKED bf16 tables from bel16.
// Predicted: main ~130-132us, WRITE ~33.8MB, FETCH ~186MB, total ~240-250.

#define DD 512
#define K3 1536
#define ROWS 128
#define LDACT 328   // 320 + 8 pad (keep %8==0: 16B-aligned rows for b128)
#define BUFS 12288  // fallback kernel: shorts per As2 buffer
#define BUFS2 16384 // v2: shorts per As buffer (4 kk * 8 rt * 64 lane * 8)

typedef short bf16x8 __attribute__((ext_vector_type(8)));
typedef float f32x4 __attribute__((ext_vector_type(4)));

__device__ inline float b2f(short s) {
    union { float f; unsigned u; } v;
    v.u = ((unsigned)(unsigned short)s) << 16;
    return v.f;
}
__device__ inline short f2b(float f) {   // RNE
    union { float fl; unsigned u; } v;
    v.fl = f;
    unsigned x = v.u;
    unsigned r = x + 0x7fffu + ((x >> 16) & 1u);
    return (short)(r >> 16);
}
__device__ inline short babsdiff(short a, short b) {
    union { float f; unsigned u; } v;
    v.f = b2f(a) - b2f(b);
    return (short)((v.u & 0x7fffffffu) >> 16);
}
__device__ __forceinline__ bf16x8 babs8(bf16x8 s, bf16x8 t) {
    bf16x8 a;
#pragma unroll
    for (int j = 0; j < 8; j++) a[j] = babsdiff(s[j], t[j]);
    return a;
}

// ---------------- old (R10) helpers for fallback ----------------
__device__ __forceinline__ int sidx32(int seg, int rt, int lane) {
    return ((seg * 8 + rt) * 64 + lane) * 8;
}
__device__ __forceinline__ void writeStage(short* buf, int rtw, int lnw, int kcb,
                                           bf16x8 s0, bf16x8 s1,
                                           bf16x8 t0, bf16x8 t1) {
    bf16x8 a0 = babs8(s0, t0), a1 = babs8(s1, t1);
    int l0 = kcb * 16 + lnw, l1 = l0 + 16;
    *(bf16x8*)&buf[sidx32(0, rtw, l0)] = s0;
    *(bf16x8*)&buf[sidx32(0, rtw, l1)] = s1;
    *(bf16x8*)&buf[sidx32(1, rtw, l0)] = t0;
    *(bf16x8*)&buf[sidx32(1, rtw, l1)] = t1;
    *(bf16x8*)&buf[sidx32(2, rtw, l0)] = a0;
    *(bf16x8*)&buf[sidx32(2, rtw, l1)] = a1;
}
__device__ __forceinline__ void stage_f32(const float* bs, const float* bt,
                                          short* buf, int rtw, int lnw, int kcb) {
#pragma unroll
    for (int c = 0; c < 2; c++) {
        bf16x8 sb, tb, ab;
#pragma unroll
        for (int h = 0; h < 2; h++) {
            float4 s4 = ((const float4*)bs)[c * 2 + h];
            float4 t4 = ((const float4*)bt)[c * 2 + h];
            float ss[4] = {s4.x, s4.y, s4.z, s4.w};
            float tt[4] = {t4.x, t4.y, t4.z, t4.w};
#pragma unroll
            for (int e = 0; e < 4; e++) {
                int j = h * 4 + e;
                sb[j] = f2b(ss[e]);
                tb[j] = f2b(tt[e]);
                ab[j] = f2b(fabsf(ss[e] - tt[e]));
            }
        }
        int l16 = (kcb + c) * 16 + lnw;
        *(bf16x8*)&buf[sidx32(0, rtw, l16)] = sb;
        *(bf16x8*)&buf[sidx32(1, rtw, l16)] = tb;
        *(bf16x8*)&buf[sidx32(2, rtw, l16)] = ab;
    }
}

// ---- workspace layout (shorts) ----
#define WT_ELEMS (320 * 1536)
#define P2T_OFF WT_ELEMS
#define R2T_OFF (WT_ELEMS + 64 * 128)
#define PREP_TOT (WT_ELEMS + 2 * 64 * 128)
#define BEL_ELEMS (8192 * 512)
#define BEL_OFF PREP_TOT
#define TBL_ELEMS (8192 * 4 * 16 * 8)   // packed bf16 table, 8MB each

// weights + beliefs -> bf16 layouts (R12 version, 8 elems/thread)
__global__ void prep_kernel(const float* __restrict__ pw1,
                            const float* __restrict__ dw1,
                            const float* __restrict__ rw1,
                            const float* __restrict__ pw2,
                            const float* __restrict__ rw2,
                            const float* __restrict__ beliefs,
                            short* __restrict__ ws, int total8) {
    int i8 = blockIdx.x * 256 + threadIdx.x;
    if (i8 >= total8) return;
    int i = i8 * 8;
    bf16x8 o;
    if (i < WT_ELEMS) {
        int n = i / K3, k = i - n * K3;   // k..k+7 share n (K3 % 8 == 0)
        const float* src;
        int stride, off;
        if (n < 128)      { src = pw1; stride = 128; off = n; }
        else if (n < 192) { src = dw1; stride = 64;  off = n - 128; }
        else              { src = rw1; stride = 128; off = n - 192; }
#pragma unroll
        for (int j = 0; j < 8; j++) o[j] = f2b(src[(k + j) * stride + off]);
    } else if (i < R2T_OFF) {
        int jj = i - P2T_OFF;
        int n = jj >> 7, k = jj & 127;
#pragma unroll
        for (int j = 0; j < 8; j++) o[j] = f2b(pw2[(k + j) * 64 + n]);
    } else if (i < PREP_TOT) {
        int jj = i - R2T_OFF;
        int n = jj >> 7, k = jj & 127;
#pragma unroll
        for (int j = 0; j < 8; j++) o[j] = f2b(rw2[(k + j) * 64 + n]);
    } else {
        const float4* b4 = (const float4*)(beliefs + (i - BEL_OFF));
        float4 x = b4[0], y = b4[1];
        float v[8] = {x.x, x.y, x.z, x.w, y.x, y.y, y.z, y.w};
#pragma unroll
        for (int j = 0; j < 8; j++) o[j] = f2b(v[j]);
    }
    *(bf16x8*)&ws[i] = o;
}

// ---- prep_bst4: packed bf16 tables from bel16. grid 512 (2 blocks/CU):
// block b -> table (b&1), rows (b>>1)*32. Bo[((r*4+w)*16+ln)*8 + ct].
__global__ __launch_bounds__(256) void prep_bst4(
    const short* __restrict__ bel16, const short* __restrict__ WT,
    short* __restrict__ BsT, short* __restrict__ BtT) {
    const int tb = blockIdx.x & 1;
    const int r0 = (blockIdx.x >> 1) * 32;
    const int t = threadIdx.x;
    const int w = t >> 6, lane = t & 63, q = lane >> 4, ln = lane & 15;
    short* Bo = tb ? BtT : BsT;
    const int koff = tb ? 512 : 0;

    f32x4 acc[5][2];
#pragma unroll
    for (int ct = 0; ct < 5; ct++)
#pragma unroll
        for (int rt = 0; rt < 2; rt++) acc[ct][rt] = (f32x4)(0.f);

#pragma unroll
    for (int k0 = 0; k0 < 512; k0 += 128)
#pragma unroll
        for (int kk = 0; kk < 4; kk++) {
            bf16x8 bfr[5];
#pragma unroll
            for (int ct = 0; ct < 5; ct++)
                bfr[ct] = *(const bf16x8*)(WT + (size_t)(w * 80 + ct * 16 + ln) * K3 +
                                           koff + k0 + kk * 32 + q * 8);
#pragma unroll
            for (int rt = 0; rt < 2; rt++) {
                bf16x8 af = *(const bf16x8*)(bel16 +
                    (size_t)(r0 + rt * 16 + ln) * DD + k0 + kk * 32 + q * 8);
#pragma unroll
                for (int ct = 0; ct < 5; ct++)
                    acc[ct][rt] = __builtin_amdgcn_mfma_f32_16x16x32_bf16(
                        af, bfr[ct], acc[ct][rt], 0, 0, 0);
            }
        }
#pragma unroll
    for (int rt = 0; rt < 2; rt++)
#pragma unroll
        for (int i = 0; i < 4; i++) {
            int r = r0 + rt * 16 + q * 4 + i;
            size_t base = ((size_t)(r * 4 + w) * 16 + ln) * 8;
#pragma unroll
            for (int ct = 0; ct < 5; ct++)
                Bo[base + ct] = f2b(acc[ct][rt][i]);
        }
}

// ---- v2 main kernel (R14, 130.7us): |s-t| @ W_a; K=512, 4 steps of 128 ----
__global__ __launch_bounds__(256, 2) void edge_main2(
    const short* __restrict__ bel16,
    const int* __restrict__ src_idx, const int* __restrict__ tgt_idx,
    const short* __restrict__ BsT, const short* __restrict__ BtT,
    const float* __restrict__ pb1, const float* __restrict__ db1,
    const float* __restrict__ rb1,
    const float* __restrict__ pb2, const float* __restrict__ pw3,
    const float* __restrict__ pb3,
    const float* __restrict__ dw2, const float* __restrict__ db2,
    const float* __restrict__ rb2,
    const short* __restrict__ WT, const short* __restrict__ pw2T,
    const short* __restrict__ rw2T,
    float* __restrict__ out, int N)
{
    // union: As dbuf 2x32KB (K-loop) / acts[64][328] (epilogue)
    __shared__ __align__(16) char smem_u[65536];
    __shared__ int sIdxR[ROWS], tIdxR[ROWS];   // raw idx, live whole kernel
    short* As = (short*)smem_u;
    short (*acts)[LDACT] = (short (*)[LDACT])smem_u;

    const int t = threadIdx.x;
    const int r0 = blockIdx.x * ROWS;
    const int w = t >> 6, lane = t & 63, q = lane >> 4, ln = lane & 15;

    if (t < ROWS) sIdxR[t] = src_idx[r0 + t];
    else tIdxR[t - ROWS] = tgt_idx[r0 + t - ROWS];
    __syncthreads();

    // staging role: pair (t,t^1) covers row rr; kh = 64-k half of the 128-k
    // step. Thread stages chunks gg = kh*8 + c (c=0..7), 8 bf16 each.
    const int rr = t >> 1, kh = t & 1;
    const int rtw = rr >> 4, lnw = rr & 15;
    const size_t srow = (size_t)sIdxR[rr] * DD + kh * 64;
    const size_t trow = (size_t)tIdxR[rr] * DD + kh * 64;

    f32x4 acc[5][8];
#pragma unroll
    for (int ct = 0; ct < 5; ct++)
#pragma unroll
        for (int rt = 0; rt < 8; rt++) acc[ct][rt] = (f32x4)(0.f);

    // prologue: stage step 0 (k0=0) |s-t| into buf0
#pragma unroll
    for (int c = 0; c < 8; c++) {
        bf16x8 s8 = *(const bf16x8*)(bel16 + srow + c * 8);
        bf16x8 t8 = *(const bf16x8*)(bel16 + trow + c * 8);
        bf16x8 a8 = babs8(s8, t8);
        int gg = kh * 8 + c, kd = gg >> 2, qd = gg & 3;
        *(bf16x8*)&As[((kd * 8 + rtw) * 64 + qd * 16 + lnw) * 8] = a8;
    }
    __syncthreads();

    // main loop: 4 K-steps of 128, one barrier per step
#pragma unroll
    for (int step = 0; step < 4; step++) {
        short* bufC = As + (step & 1) * BUFS2;
        short* bufN = As + ((step & 1) ^ 1) * BUFS2;
        const int k0 = step * 128;
        const bool pf = (step < 3);
        bf16x8 ps0, ps1, pt0, pt1;   // in-flight batch (2 chunks, 16 regs)

#pragma unroll
        for (int kk = 0; kk < 4; kk++) {
            bf16x8 bfr[5];
#pragma unroll
            for (int ct = 0; ct < 5; ct++)
                bfr[ct] = *(const bf16x8*)(WT + (size_t)(w * 80 + ct * 16 + ln) * K3 +
                                           1024 + k0 + kk * 32 + q * 8);
            // staging region: bfr issued first (older) -> MFMA bfr waits are
            // counted vmcnt(>=4), prefetch gathers (newer) stay in flight.
            __builtin_amdgcn_sched_barrier(0);
            if (pf) {
                if (kk > 0) {   // consume batch kk-1 -> chunks 2(kk-1),2(kk-1)+1
                    bf16x8 a0 = babs8(ps0, pt0), a1 = babs8(ps1, pt1);
                    int g0 = kh * 8 + 2 * (kk - 1);
                    int kd0 = g0 >> 2, qd0 = g0 & 3;
                    int g1 = g0 + 1, kd1 = g1 >> 2, qd1 = g1 & 3;
                    *(bf16x8*)&bufN[((kd0 * 8 + rtw) * 64 + qd0 * 16 + lnw) * 8] = a0;
                    *(bf16x8*)&bufN[((kd1 * 8 + rtw) * 64 + qd1 * 16 + lnw) * 8] = a1;
                }
                // issue batch kk: next step's chunks 2kk, 2kk+1
                ps0 = *(const bf16x8*)(bel16 + srow + k0 + 128 + (2 * kk) * 8);
                ps1 = *(const bf16x8*)(bel16 + srow + k0 + 128 + (2 * kk + 1) * 8);
                pt0 = *(const bf16x8*)(bel16 + trow + k0 + 128 + (2 * kk) * 8);
                pt1 = *(const bf16x8*)(bel16 + trow + k0 + 128 + (2 * kk + 1) * 8);
            }
            __builtin_amdgcn_sched_barrier(0);
            __builtin_amdgcn_s_setprio(1);
#pragma unroll
            for (int rt = 0; rt < 8; rt++) {
                bf16x8 af = *(const bf16x8*)&bufC[((kk * 8 + rt) * 64 + lane) * 8];
#pragma unroll
                for (int ct = 0; ct < 5; ct++)
                    acc[ct][rt] = __builtin_amdgcn_mfma_f32_16x16x32_bf16(
                        af, bfr[ct], acc[ct][rt], 0, 0, 0);
            }
            __builtin_amdgcn_s_setprio(0);
        }
        if (pf) {   // final consume: batch 3 -> chunks 6,7
            bf16x8 a0 = babs8(ps0, pt0), a1 = babs8(ps1, pt1);
            int g0 = kh * 8 + 6;
            int kd0 = g0 >> 2, qd0 = g0 & 3;
            int g1 = g0 + 1, kd1 = g1 >> 2, qd1 = g1 & 3;
            *(bf16x8*)&bufN[((kd0 * 8 + rtw) * 64 + qd0 * 16 + lnw) * 8] = a0;
            *(bf16x8*)&bufN[((kd1 * 8 + rtw) * 64 + qd1 * 16 + lnw) * 8] = a1;
        }
        __syncthreads();
    }

    // ---- epilogue: two 64-row halves; acc + Bs[src] + Bt[tgt] + bias ----
#pragma unroll
    for (int hh = 0; hh < 2; hh++) {
        float bias5[5];
#pragma unroll
        for (int ct = 0; ct < 5; ct++) {
            int col = w * 80 + ct * 16 + ln;
            bias5[ct] = (col < 128) ? pb1[col]
                      : (col < 192) ? db1[col - 128]
                                    : rb1[col - 192];
        }
#pragma unroll
        for (int rt4 = 0; rt4 < 4; rt4++) {
            // packed-table loads: 1 b128 per row per table
            bf16x8 bs8[4], bt8[4];
#pragma unroll
            for (int i = 0; i < 4; i++) {
                int gr = hh * 64 + rt4 * 16 + q * 4 + i;
                bs8[i] = *(const bf16x8*)(BsT +
                    ((size_t)(sIdxR[gr] * 4 + w) * 16 + ln) * 8);
                bt8[i] = *(const bf16x8*)(BtT +
                    ((size_t)(tIdxR[gr] * 4 + w) * 16 + ln) * 8);
            }
#pragma unroll
            for (int i = 0; i < 4; i++) {
                int lrow = rt4 * 16 + q * 4 + i;
#pragma unroll
                for (int ct = 0; ct < 5; ct++) {
                    float v = acc[ct][hh * 4 + rt4][i] +
                              b2f(bs8[i][ct]) + b2f(bt8[i][ct]) + bias5[ct];
                    acts[lrow][w * 80 + ct * 16 + ln] = f2b(fmaxf(v, 0.f));
                }
            }
        }
        __syncthreads();

        // C1: relations = relu1_r[64x128] @ rw2 + rb2 (reads acts 192..319)
        {
            f32x4 rc[4];
#pragma unroll
            for (int rt = 0; rt < 4; rt++) rc[rt] = (f32x4)(0.f);
#pragma unroll
            for (int ks = 0; ks < 4; ks++) {
                bf16x8 bfr = *(const bf16x8*)(rw2T + (w * 16 + ln) * 128 +
                                              ks * 32 + q * 8);
#pragma unroll
                for (int rt = 0; rt < 4; rt++) {
                    bf16x8 afr = *(const bf16x8*)&acts[rt * 16 + ln][192 + ks * 32 + q * 8];
                    rc[rt] = __builtin_amdgcn_mfma_f32_16x16x32_bf16(afr, bfr, rc[rt], 0, 0, 0);
                }
            }
            int col = w * 16 + ln;
            float bias = rb2[col];
            float* rel = out + 2 * (size_t)N;
#pragma unroll
            for (int rt = 0; rt < 4; rt++)
#pragma unroll
                for (int i = 0; i < 4; i++) {
                    int grow = r0 + hh * 64 + rt * 16 + q * 4 + i;
                    rel[(size_t)grow * 64 + col] = rc[rt][i] + bias;
                }
        }

        // C2: pc = relu1_p[64x128] @ pw2 (reads acts 0..127) -> regs
        f32x4 pc[4];
        {
#pragma unroll
            for (int rt = 0; rt < 4; rt++) pc[rt] = (f32x4)(0.f);
#pragma unroll
            for (int ks = 0; ks < 4; ks++) {
                bf16x8 bfr = *(const bf16x8*)(pw2T + (w * 16 + ln) * 128 +
                                              ks * 32 + q * 8);
#pragma unroll
                for (int rt = 0; rt < 4; rt++) {
                    bf16x8 afr = *(const bf16x8*)&acts[rt * 16 + ln][0 + ks * 32 + q * 8];
                    pc[rt] = __builtin_amdgcn_mfma_f32_16x16x32_bf16(afr, bfr, pc[rt], 0, 0, 0);
                }
            }
        }
        __syncthreads();   // all C2 reads of acts cols 0..127 complete

        // write h2 = relu(pc + pb2) into acts cols 0..63 (now dead)
        {
            int col = w * 16 + ln;
            float bias = pb2[col];
#pragma unroll
            for (int rt = 0; rt < 4; rt++)
#pragma unroll
                for (int i = 0; i < 4; i++) {
                    int lrow = rt * 16 + q * 4 + i;
                    acts[lrow][col] = f2b(fmaxf(pc[rt][i] + bias, 0.f));
                }
        }
        __syncthreads();   // h2 visible

        // C3: probs (acts[.][0..63]); C4: dirs (acts[.][128..191]).
        // 2 lanes per row (shfl_xor) -> all 256 threads active.
        {
            int role = t >> 7;            // 0: probs, 1: directions
            int rloc = (t & 127) >> 1;    // row 0..63
            int kq = t & 1;               // 32-k half
            float s = 0.f;
            if (role == 0) {
#pragma unroll
                for (int j = 0; j < 32; j++)
                    s += b2f(acts[rloc][kq * 32 + j]) * pw3[kq * 32 + j];
            } else {
#pragma unroll
                for (int j = 0; j < 32; j++)
                    s += b2f(acts[rloc][128 + kq * 32 + j]) * dw2[kq * 32 + j];
            }
            s += __shfl_xor(s, 1);
            if (kq == 0) {
                if (role == 0) {
                    float pr = 1.f / (1.f + __expf(-(s + pb3[0])));
                    out[r0 + hh * 64 + rloc] = pr;
                } else {
                    float dir = (1.f / (1.f + __expf(-(s + db2[0])))) *
                                1.57079632679489662f;
                    out[(size_t)N + r0 + hh * 64 + rloc] = dir;
                }
            }
        }
        __syncthreads();   // protect acts before next half overwrites
    }
}

// ---------------- old (R10) main kernel: ws fallback ----------------
template<bool BF>
__global__ __launch_bounds__(256, 2) void edge_main(
    const float* __restrict__ beliefs, const short* __restrict__ bel16,
    const int* __restrict__ src_idx, const int* __restrict__ tgt_idx,
    const float* __restrict__ pb1, const float* __restrict__ db1,
    const float* __restrict__ rb1,
    const float* __restrict__ pb2, const float* __restrict__ pw3,
    const float* __restrict__ pb3,
    const float* __restrict__ dw2, const float* __restrict__ db2,
    const float* __restrict__ rb2,
    const short* __restrict__ WT, const short* __restrict__ pw2T,
    const short* __restrict__ rw2T,
    float* __restrict__ out, int N)
{
    __shared__ __align__(16) char smem_u[49152];
    short* As2 = (short*)smem_u;
    short (*acts)[LDACT] = (short (*)[LDACT])smem_u;
    int* sIdx = (int*)smem_u;
    int* tIdx = sIdx + ROWS;

    const int t = threadIdx.x;
    const int r0 = blockIdx.x * ROWS;
    const int w = t >> 6, lane = t & 63, q = lane >> 4, ln = lane & 15;

    if (t < ROWS) sIdx[t] = src_idx[r0 + t] * DD;
    else tIdx[t - ROWS] = tgt_idx[r0 + t - ROWS] * DD;
    __syncthreads();

    const int rrow = t >> 1, kh = t & 1;
    const int rtw = rrow >> 4, lnw = rrow & 15;
    const int kcb = kh * 2;
    const int srow = sIdx[rrow], trow = tIdx[rrow];
    __syncthreads();

    f32x4 acc[5][8];
#pragma unroll
    for (int ct = 0; ct < 5; ct++)
#pragma unroll
        for (int rt = 0; rt < 8; rt++) acc[ct][rt] = (f32x4)(0.f);

    bf16x8 bfr0[5];
#pragma unroll
    for (int ct = 0; ct < 5; ct++) {
        int col = w * 80 + ct * 16 + ln;
        bfr0[ct] = *(const bf16x8*)(WT + (size_t)col * K3 + q * 8);
    }
    if constexpr (BF) {
        const bf16x8* pS = (const bf16x8*)(bel16 + srow + kh * 16);
        const bf16x8* pT = (const bf16x8*)(bel16 + trow + kh * 16);
        writeStage(As2, rtw, lnw, kcb, pS[0], pS[1], pT[0], pT[1]);
    } else {
        stage_f32(beliefs + srow + kh * 16, beliefs + trow + kh * 16,
                  As2, rtw, lnw, kcb);
    }
    __syncthreads();

    for (int step = 0; step < 16; ++step) {
        short* bufC = As2 + (step & 1) * BUFS;
        short* bufN = As2 + ((step & 1) ^ 1) * BUFS;
        const int k0 = step * 32;
        const bool pf = (step < 15);
        bf16x8 ns0, ns1, nt0, nt1;

#pragma unroll
        for (int seg = 0; seg < 3; seg++) {
            bf16x8 bfr[5];
            if (seg == 0) {
#pragma unroll
                for (int ct = 0; ct < 5; ct++) bfr[ct] = bfr0[ct];
            } else {
#pragma unroll
                for (int ct = 0; ct < 5; ct++) {
                    int col = w * 80 + ct * 16 + ln;
                    bfr[ct] = *(const bf16x8*)(WT + (size_t)col * K3 +
                                               seg * DD + k0 + q * 8);
                }
            }
            if (seg == 2) {
                __builtin_amdgcn_sched_barrier(0);
                if (pf) {
                    if constexpr (BF) {
                        const bf16x8* pS = (const bf16x8*)(bel16 + srow + k0 + 32 + kh * 16);
                        const bf16x8* pT = (const bf16x8*)(bel16 + trow + k0 + 32 + kh * 16);
                        ns0 = pS[0]; ns1 = pS[1]; nt0 = pT[0]; nt1 = pT[1];
                    }
#pragma unroll
                    for (int ct = 0; ct < 5; ct++) {
                        int col = w * 80 + ct * 16 + ln;
                        bfr0[ct] = *(const bf16x8*)(WT + (size_t)col * K3 +
                                                    k0 + 32 + q * 8);
                    }
                }
                __builtin_amdgcn_sched_barrier(0);
            }
            __builtin_amdgcn_s_setprio(1);
#pragma unroll
            for (int rt = 0; rt < 8; rt++) {
                bf16x8 af = *(const bf16x8*)&bufC[sidx32(seg, rt, lane)];
#pragma unroll
                for (int ct = 0; ct < 5; ct++)
                    acc[ct][rt] = __builtin_amdgcn_mfma_f32_16x16x32_bf16(
                        af, bfr[ct], acc[ct][rt], 0, 0, 0);
            }
            __builtin_amdgcn_s_setprio(0);
        }
        if constexpr (BF) {
            if (pf) writeStage(bufN, rtw, lnw, kcb, ns0, ns1, nt0, nt1);
        } else {
            if (pf) stage_f32(beliefs + srow + k0 + 32 + kh * 16,
                              beliefs + trow + k0 + 32 + kh * 16,
                              bufN, rtw, lnw, kcb);
        }
        __syncthreads();
    }

#pragma unroll
    for (int h = 0; h < 2; h++) {
#pragma unroll
        for (int ct = 0; ct < 5; ct++) {
            int col = w * 80 + ct * 16 + ln;
            float bias = (col < 128) ? pb1[col]
                       : (col < 192) ? db1[col - 128]
                                     : rb1[col - 192];
#pragma unroll
            for (int rt4 = 0; rt4 < 4; rt4++)
#pragma unroll
                for (int i = 0; i < 4; i++) {
                    int lrow = rt4 * 16 + q * 4 + i;
                    float v = acc[ct][h * 4 + rt4][i] + bias;
                    acts[lrow][col] = f2b(fmaxf(v, 0.f));
                }
        }
        __syncthreads();
        {
            f32x4 rc[4];
#pragma unroll
            for (int rt = 0; rt < 4; rt++) rc[rt] = (f32x4)(0.f);
#pragma unroll
            for (int ks = 0; ks < 4; ks++) {
                bf16x8 bfr = *(const bf16x8*)(rw2T + (w * 16 + ln) * 128 +
                                              ks * 32 + q * 8);
#pragma unroll
                for (int rt = 0; rt < 4; rt++) {
                    bf16x8 afr = *(const bf16x8*)&acts[rt * 16 + ln][192 + ks * 32 + q * 8];
                    rc[rt] = __builtin_amdgcn_mfma_f32_16x16x32_bf16(afr, bfr, rc[rt], 0, 0, 0);
                }
            }
            int col = w * 16 + ln;
            float bias = rb2[col];
            float* rel = out + 2 * (size_t)N;
#pragma unroll
            for (int rt = 0; rt < 4; rt++)
#pragma unroll
                for (int i = 0; i < 4; i++) {
                    int grow = r0 + h * 64 + rt * 16 + q * 4 + i;
                    rel[(size_t)grow * 64 + col] = rc[rt][i] + bias;
                }
        }
        f32x4 pc[4];
        {
#pragma unroll
            for (int rt = 0; rt < 4; rt++) pc[rt] = (f32x4)(0.f);
#pragma unroll
            for (int ks = 0; ks < 4; ks++) {
                bf16x8 bfr = *(const bf16x8*)(pw2T + (w * 16 + ln) * 128 +
                                              ks * 32 + q * 8);
#pragma unroll
                for (int rt = 0; rt < 4; rt++) {
                    bf16x8 afr = *(const bf16x8*)&acts[rt * 16 + ln][0 + ks * 32 + q * 8];
                    pc[rt] = __builtin_amdgcn_mfma_f32_16x16x32_bf16(afr, bfr, pc[rt], 0, 0, 0);
                }
            }
        }
        __syncthreads();
        {
            int col = w * 16 + ln;
            float bias = pb2[col];
#pragma unroll
            for (int rt = 0; rt < 4; rt++)
#pragma unroll
                for (int i = 0; i < 4; i++) {
                    int lrow = rt * 16 + q * 4 + i;
                    acts[lrow][col] = f2b(fmaxf(pc[rt][i] + bias, 0.f));
                }
        }
        __syncthreads();
        if (t < 64) {
            float s = pb3[0];
#pragma unroll 8
            for (int k = 0; k < 64; k++) s += b2f(acts[t][k]) * pw3[k];
            float pr = 1.f / (1.f + __expf(-s));
            out[r0 + h * 64 + t] = pr;
        } else if (t < 128) {
            int lrow = t - 64;
            float s = db2[0];
#pragma unroll 8
            for (int k = 0; k < 64; k++) s += b2f(acts[lrow][128 + k]) * dw2[k];
            float dir = (1.f / (1.f + __expf(-s))) * 1.57079632679489662f;
            out[(size_t)N + r0 + h * 64 + lrow] = dir;
        }
        __syncthreads();
    }
}

extern "C" void kernel_launch(void* const* d_in, const int* in_sizes, int n_in,
                              void* d_out, int out_size, void* d_ws, size_t ws_size,
                              hipStream_t stream) {
    const float* beliefs = (const float*)d_in[0];
    const int* src = (const int*)d_in[1];
    const int* tgt = (const int*)d_in[2];
    const float* pw1 = (const float*)d_in[3];
    const float* pb1 = (const float*)d_in[4];
    const float* pw2 = (const float*)d_in[5];
    const float* pb2 = (const float*)d_in[6];
    const float* pw3 = (const float*)d_in[7];
    const float* pb3 = (const float*)d_in[8];
    const float* dw1 = (const float*)d_in[9];
    const float* db1 = (const float*)d_in[10];
    const float* dw2 = (const float*)d_in[11];
    const float* db2 = (const float*)d_in[12];
    const float* rw1 = (const float*)d_in[13];
    const float* rb1 = (const float*)d_in[14];
    const float* rw2 = (const float*)d_in[15];
    const float* rb2 = (const float*)d_in[16];

    short* ws = (short*)d_ws;
    short* WT    = ws;
    short* pw2T  = ws + P2T_OFF;
    short* rw2T  = ws + R2T_OFF;
    short* bel16 = ws + BEL_OFF;
    const int N = in_sizes[1];

    const size_t BF_BYTES = (size_t)(PREP_TOT + BEL_ELEMS) * sizeof(short);
    const size_t V2_BYTES = BF_BYTES + (size_t)2 * TBL_ELEMS * sizeof(short);
    const bool useV2 = ws_size >= V2_BYTES;
    const bool useBf = ws_size >= BF_BYTES;

    if (useV2) {
        // R12-shape chain: full prep (weights + bel16) -> tables -> main
        const int prep8 = (PREP_TOT + BEL_ELEMS) / 8;
        prep_kernel<<<(prep8 + 255) / 256, 256, 0, stream>>>(
            pw1, dw1, rw1, pw2, rw2, beliefs, ws, prep8);
        short* BsT = ws + PREP_TOT + BEL_ELEMS;
        short* BtT = BsT + TBL_ELEMS;
        prep_bst4<<<512, 256, 0, stream>>>(bel16, WT, BsT, BtT);
        edge_main2<<<N / ROWS, 256, 0, stream>>>(
            bel16, src, tgt, BsT, BtT,
            pb1, db1, rb1, pb2, pw3, pb3, dw2, db2, rb2,
            WT, pw2T, rw2T, (float*)d_out, N);
    } else {
        const int prepElems = useBf ? (PREP_TOT + BEL_ELEMS) : PREP_TOT;
        const int prep8 = prepElems / 8;
        prep_kernel<<<(prep8 + 255) / 256, 256, 0, stream>>>(
            pw1, dw1, rw1, pw2, rw2, beliefs, ws, prep8);
        if (useBf)
            edge_main<true><<<N / ROWS, 256, 0, stream>>>(
                beliefs, bel16, src, tgt, pb1, db1, rb1, pb2, pw3, pb3,
                dw2, db2, rb2, WT, pw2T, rw2T, (float*)d_out, N);
        else
            edge_main<false><<<N / ROWS, 256, 0, stream>>>(
                beliefs, bel16, src, tgt, pb1, db1, rb1, pb2, pw3, pb3,
                dw2, db2, rb2, WT, pw2T, rw2T, (float*)d_out, N);
    }
}